// Round 1
// baseline (178.213 us; speedup 1.0000x reference)
//
#include <hip/hip_runtime.h>
#include <math.h>

#define FS      76
#define NCELLP  (FS*FS)        // 5776 cells per (b,a) plane
#define NA      3
#define NCH     85
#define NB      16
#define NLAB    100
#define NCLS    80
#define BLK     256
#define GX      ((NCELLP + BLK - 1) / BLK)   // 23
#define NBLK    (GX * NA * NB)               // 1104 blocks -> partials

__device__ __forceinline__ float sigf(float z) { return 1.0f / (1.0f + expf(-z)); }

// bce(x,t) = -(t*max(log x,-100) + (1-t)*max(log(1-x),-100)), matching reference fp32 math
__device__ __forceinline__ float bcef(float x, float t) {
    return -(t * fmaxf(logf(x), -100.0f) + (1.0f - t) * fmaxf(logf(1.0f - x), -100.0f));
}

__global__ __launch_bounds__(BLK) void k_main(const float* __restrict__ x,
                                              const float* __restrict__ labels,
                                              double* __restrict__ part)
{
    // masked anchors = ANCHORS_PX / 608 / 8; /8 is exact (pow2) so single-divide constant is identical
    const float AW[3] = {13.0f/4864.0f, 28.0f/4864.0f, 62.0f/4864.0f};
    const float AH[3] = {16.0f/4864.0f, 32.0f/4864.0f, 35.0f/4864.0f};

    __shared__ float4 s_box[NLAB];   // (x1,y1,x2,y2) of label box, cxcywh->corners precomputed
    __shared__ float  s_area[NLAB];  // lw*lh
    __shared__ int    s_flat[NLAB];  // best_n*5776 + lj*76 + li
    __shared__ float  s_tx[NLAB], s_tw[NLAB], s_th[NLAB], s_sv[NLAB];
    __shared__ int    s_cls[NLAB];
    __shared__ double s_red[BLK/64][5];

    const int a = blockIdx.y, b = blockIdx.z;
    const int tid = threadIdx.x;

    // ---- per-label prep (redundant per block; trivial cost) ----
    if (tid < NLAB) {
        const float* L = labels + (size_t)(b * NLAB + tid) * 5;
        const float lx = (L[0] + L[2]) * 0.0625f;   // /(STRIDE*2) exact pow2
        const float ly = (L[1] + L[3]) * 0.0625f;
        const float lw = L[2] * 0.125f;             // /STRIDE exact pow2
        const float lh = L[3] * 0.125f;
        const int li = (int)lx, lj = (int)ly;

        // CIoU argmax vs ref_anchors [0,0,aw,ah], first-max wins (strict >)
        const float area_a = lw * lh;
        const float ata = atanf(lw / fmaxf(lh, 1e-16f));
        const float V4PI2 = (float)(4.0 / (M_PI * M_PI));
        float best = -1e30f; int bn = 0;
        #pragma unroll
        for (int n = 0; n < NA; n++) {
            const float aw = AW[n], ah = AH[n];
            const float brx = fminf(lw, aw), bry = fminf(lh, ah);
            const float ai  = (0.0f < brx && 0.0f < bry) ? brx * bry : 0.0f;
            const float iou = ai / fmaxf(area_a + aw * ah - ai, 1e-16f);
            const float dx = (lw - aw) * 0.5f, dy = (lh - ah) * 0.5f;
            const float rho2 = dx * dx + dy * dy;
            const float cx = fmaxf(lw, aw), cy = fmaxf(lh, ah);
            const float c2 = cx * cx + cy * cy;
            const float da = ata - atanf(aw / fmaxf(ah, 1e-16f));
            const float v = V4PI2 * da * da;
            const float alpha = v / fmaxf(1.0f - iou + v, 1e-16f);
            const float ciou = iou - rho2 / fmaxf(c2, 1e-16f) - alpha * v;
            if (ciou > best) { best = ciou; bn = n; }
        }
        s_box[tid]  = make_float4(lx - lw * 0.5f, ly - lh * 0.5f,
                                  lx + lw * 0.5f, ly + lh * 0.5f);
        s_area[tid] = area_a;
        s_flat[tid] = bn * NCELLP + lj * FS + li;
        s_tx[tid]   = lx - truncf(lx);
        s_tw[tid]   = logf(lw / AW[bn] + 1e-16f);
        s_th[tid]   = logf(lh / AH[bn] + 1e-16f);
        s_sv[tid]   = sqrtf(2.0f - area_a / (float)NCELLP);
        s_cls[tid]  = (int)L[4];
    }
    __syncthreads();

    // ---- per-cell loss ----
    const int p = blockIdx.x * BLK + tid;
    double axy = 0.0, awh = 0.0, aobj = 0.0, acls = 0.0, al2 = 0.0;

    if (p < NCELLP) {
        const int j = p / FS, i = p - j * FS;
        const float* xb = x + ((size_t)(b * NA + a) * NCH) * NCELLP + p;
        const float o0 = xb[0];
        const float o1 = xb[(size_t)1 * NCELLP];
        const float o2 = xb[(size_t)2 * NCELLP];
        const float o3 = xb[(size_t)3 * NCELLP];
        const float o4 = xb[(size_t)4 * NCELLP];
        const float s0 = sigf(o0), s1 = sigf(o1), s4 = sigf(o4);
        const float px = s0 + (float)i, py = s1 + (float)j;
        const float pw = expf(o2 * AW[a]), ph = expf(o3 * AH[a]);
        const float px1 = px - pw * 0.5f, px2 = px + pw * 0.5f;
        const float py1 = py - ph * 0.5f, py2 = py + ph * 0.5f;
        const float pa = pw * ph;

        bool anyhit = false;
        int win = -1;                       // last matching label wins (.set scatter semantics)
        const int myflat = a * NCELLP + p;
        for (int l = 0; l < NLAB; l++) {
            const float4 bb = s_box[l];
            const float tlx = fmaxf(px1, bb.x);
            const float tly = fmaxf(py1, bb.y);
            const float brx = fminf(px2, bb.z);
            const float bry = fminf(py2, bb.w);
            const float ai = (tlx < brx && tly < bry) ? (brx - tlx) * (bry - tly) : 0.0f;
            const float den = pa + s_area[l] - ai;
            anyhit = anyhit || (2.0f * ai > den);   // iou > 0.5, division-free
            if (s_flat[l] == myflat) win = l;
        }

        float obj = anyhit ? 0.0f : 1.0f;
        if (win >= 0) obj = 1.0f;

        if (obj != 0.0f) {
            const float t4 = (win >= 0) ? 1.0f : 0.0f;
            aobj += (double)bcef(s4, t4);
            const float d4 = s4 - t4;            // o4m - t4 with obj=1
            al2 += (double)(d4 * d4);
        }
        if (win >= 0) {
            const float tx = s_tx[win], tw = s_tw[win], th = s_th[win], sv = s_sv[win];
            const int cls = s_cls[win];
            const float w2 = sv * sv;
            axy += (double)(w2 * (bcef(s0, tx) + bcef(s1, tx)));
            const float dw = (o2 - tw) * sv, dh = (o3 - th) * sv;
            awh += (double)(dw * dw + dh * dh);        // /2 applied at finalize
            const float d0 = s0 - tx, d1 = s1 - tx;
            al2 += (double)(d0 * d0 + d1 * d1 + dw * dw + dh * dh);
            for (int c = 0; c < NCLS; c++) {
                const float sc = sigf(xb[(size_t)(5 + c) * NCELLP]);
                const float t = (c == cls) ? 1.0f : 0.0f;
                acls += (double)bcef(sc, t);
                const float dc = sc - t;
                al2 += (double)(dc * dc);
            }
        }
    }

    // ---- deterministic block reduction: wave shuffle -> LDS -> partial ----
    double v[5] = {axy, awh, aobj, acls, al2};
    #pragma unroll
    for (int k = 0; k < 5; k++) {
        double t = v[k];
        for (int off = 32; off > 0; off >>= 1) t += __shfl_down(t, off, 64);
        v[k] = t;
    }
    const int wave = tid >> 6, lane = tid & 63;
    if (lane == 0) {
        #pragma unroll
        for (int k = 0; k < 5; k++) s_red[wave][k] = v[k];
    }
    __syncthreads();
    if (tid == 0) {
        const int bid = blockIdx.x + GX * (blockIdx.y + NA * blockIdx.z);
        #pragma unroll
        for (int k = 0; k < 5; k++) {
            double s = 0.0;
            for (int w = 0; w < BLK/64; w++) s += s_red[w][k];
            part[(size_t)bid * 5 + k] = s;
        }
    }
}

__global__ __launch_bounds__(256) void k_final(const double* __restrict__ part,
                                               float* __restrict__ out)
{
    __shared__ double s_red[4][5];
    const int tid = threadIdx.x;
    double v[5] = {0, 0, 0, 0, 0};
    for (int r = tid; r < NBLK; r += 256) {
        #pragma unroll
        for (int k = 0; k < 5; k++) v[k] += part[(size_t)r * 5 + k];
    }
    #pragma unroll
    for (int k = 0; k < 5; k++) {
        double t = v[k];
        for (int off = 32; off > 0; off >>= 1) t += __shfl_down(t, off, 64);
        v[k] = t;
    }
    const int wave = tid >> 6, lane = tid & 63;
    if (lane == 0) {
        #pragma unroll
        for (int k = 0; k < 5; k++) s_red[wave][k] = v[k];
    }
    __syncthreads();
    if (tid == 0) {
        double xy = 0, wh = 0, ob = 0, cl = 0, l2 = 0;
        for (int w = 0; w < 4; w++) {
            xy += s_red[w][0]; wh += s_red[w][1]; ob += s_red[w][2];
            cl += s_red[w][3]; l2 += s_red[w][4];
        }
        wh *= 0.5;  // loss_wh = sum/2
        out[0] = (float)(xy + wh + ob + cl);
        out[1] = (float)xy;
        out[2] = (float)wh;
        out[3] = (float)ob;
        out[4] = (float)cl;
        out[5] = (float)l2;
    }
}

extern "C" void kernel_launch(void* const* d_in, const int* in_sizes, int n_in,
                              void* d_out, int out_size, void* d_ws, size_t ws_size,
                              hipStream_t stream) {
    const float* x      = (const float*)d_in[0];
    const float* labels = (const float*)d_in[1];
    double* part = (double*)d_ws;   // NBLK*5 doubles = 44,160 B of scratch

    dim3 grid(GX, NA, NB);
    k_main<<<grid, BLK, 0, stream>>>(x, labels, part);
    k_final<<<1, 256, 0, stream>>>(part, (float*)d_out);
}

// Round 2
// 132.361 us; speedup vs baseline: 1.3464x; 1.3464x over previous
//
#include <hip/hip_runtime.h>
#include <math.h>

#define FS      76
#define NCELLP  (FS*FS)        // 5776 cells per (b,a) plane
#define NA      3
#define NCH     85
#define NB      16
#define NLAB    100
#define NCLS    80
#define BLK     256
#define GX      ((NCELLP + BLK - 1) / BLK)   // 23
#define NBLK    (GX * NA * NB)               // 1104 blocks -> partials

__device__ __forceinline__ float sigf(float z) { return 1.0f / (1.0f + expf(-z)); }

// bce(x,t) = -(t*max(log x,-100) + (1-t)*max(log(1-x),-100)), matching reference fp32 math
__device__ __forceinline__ float bcef(float x, float t) {
    return -(t * fmaxf(logf(x), -100.0f) + (1.0f - t) * fmaxf(logf(1.0f - x), -100.0f));
}

__global__ __launch_bounds__(BLK) void k_main(const float* __restrict__ x,
                                              const float* __restrict__ labels,
                                              double* __restrict__ part)
{
    // masked anchors = ANCHORS_PX / 608 / 8 (exact pow2 divide -> single constant)
    const float AW[3] = {13.0f/4864.0f, 28.0f/4864.0f, 62.0f/4864.0f};
    const float AH[3] = {16.0f/4864.0f, 32.0f/4864.0f, 35.0f/4864.0f};

    __shared__ float4 s_box[NLAB];     // label box corners (x1,y1,x2,y2)
    __shared__ float  s_area[NLAB];    // lw*lh
    __shared__ int    s_flat[NLAB];    // best_n*5776 + lj*76 + li
    __shared__ float  s_tx[NLAB], s_tw[NLAB], s_th[NLAB], s_sv[NLAB];
    __shared__ int    s_cls[NLAB];
    __shared__ int    s_win[BLK];      // per-cell winning label (max index = last .set wins)
    __shared__ float4 s_cbox[NLAB];    // compacted candidate boxes (la < 2*pa_max)
    __shared__ float  s_carea[NLAB];
    __shared__ int    s_ncand, s_nw;
    __shared__ int    s_wlist[BLK];    // packed (cell_tid<<16)|win
    __shared__ float  s_pmax[BLK/64];
    __shared__ float  s_red[BLK/64][5];

    const int a = blockIdx.y, b = blockIdx.z;
    const int tid = threadIdx.x;

    // ---- stage A: init + per-label prep ----
    s_win[tid] = -1;
    if (tid == 0) { s_ncand = 0; s_nw = 0; }
    if (tid < NLAB) {
        const float* L = labels + (size_t)(b * NLAB + tid) * 5;
        const float lx = (L[0] + L[2]) * 0.0625f;   // /(STRIDE*2)
        const float ly = (L[1] + L[3]) * 0.0625f;
        const float lw = L[2] * 0.125f;             // /STRIDE
        const float lh = L[3] * 0.125f;
        const int li = (int)lx, lj = (int)ly;

        // CIoU argmax vs ref_anchors [0,0,aw,ah], first-max wins (strict >)
        const float area_a = lw * lh;
        const float ata = atanf(lw / fmaxf(lh, 1e-16f));
        const float V4PI2 = (float)(4.0 / (M_PI * M_PI));
        float best = -1e30f; int bn = 0;
        #pragma unroll
        for (int n = 0; n < NA; n++) {
            const float aw = AW[n], ah = AH[n];
            const float brx = fminf(lw, aw), bry = fminf(lh, ah);
            const float ai  = (0.0f < brx && 0.0f < bry) ? brx * bry : 0.0f;
            const float iou = ai / fmaxf(area_a + aw * ah - ai, 1e-16f);
            const float dx = (lw - aw) * 0.5f, dy = (lh - ah) * 0.5f;
            const float rho2 = dx * dx + dy * dy;
            const float cx = fmaxf(lw, aw), cy = fmaxf(lh, ah);
            const float c2 = cx * cx + cy * cy;
            const float da = ata - atanf(aw / fmaxf(ah, 1e-16f));
            const float v = V4PI2 * da * da;
            const float alpha = v / fmaxf(1.0f - iou + v, 1e-16f);
            const float ciou = iou - rho2 / fmaxf(c2, 1e-16f) - alpha * v;
            if (ciou > best) { best = ciou; bn = n; }
        }
        s_box[tid]  = make_float4(lx - lw * 0.5f, ly - lh * 0.5f,
                                  lx + lw * 0.5f, ly + lh * 0.5f);
        s_area[tid] = area_a;
        s_flat[tid] = bn * NCELLP + lj * FS + li;
        s_tx[tid]   = lx - truncf(lx);
        s_tw[tid]   = logf(lw / AW[bn] + 1e-16f);
        s_th[tid]   = logf(lh / AH[bn] + 1e-16f);
        s_sv[tid]   = sqrtf(2.0f - area_a / (float)NCELLP);
        s_cls[tid]  = (int)L[4];
    }
    __syncthreads();

    // ---- stage B: channel loads, win scatter, block pa_max ----
    const int p = blockIdx.x * BLK + tid;
    const bool live = (p < NCELLP);
    const int pc = live ? p : (NCELLP - 1);
    const float* xb = x + ((size_t)(b * NA + a) * NCH) * NCELLP + pc;
    const float o0 = xb[0];
    const float o1 = xb[(size_t)1 * NCELLP];
    const float o2 = xb[(size_t)2 * NCELLP];
    const float o3 = xb[(size_t)3 * NCELLP];
    const float o4 = xb[(size_t)4 * NCELLP];
    const float s0 = sigf(o0), s1 = sigf(o1), s4 = sigf(o4);
    const float pw = expf(o2 * AW[a]), ph = expf(o3 * AH[a]);
    const float pa = live ? pw * ph : 0.0f;

    if (tid < NLAB) {
        const int idx = s_flat[tid] - (a * NCELLP + blockIdx.x * BLK);
        if (idx >= 0 && idx < BLK) atomicMax(&s_win[idx], tid);
    }
    float m = pa;
    #pragma unroll
    for (int off = 32; off > 0; off >>= 1) m = fmaxf(m, __shfl_xor(m, off, 64));
    if ((tid & 63) == 0) s_pmax[tid >> 6] = m;
    __syncthreads();
    const float pmax = fmaxf(fmaxf(s_pmax[0], s_pmax[1]), fmaxf(s_pmax[2], s_pmax[3]));

    // exact prune: iou>0.5 needs 3*ai > pa+la with ai<=min(pa,la) => la < 2*pa <= 2*pmax
    if (tid < NLAB && s_area[tid] < 2.0f * pmax) {
        const int q = atomicAdd(&s_ncand, 1);
        s_cbox[q] = s_box[tid];
        s_carea[q] = s_area[tid];
    }
    __syncthreads();

    // ---- stage C: per-cell loss ----
    float axy = 0.f, awh = 0.f, aobj = 0.f, acls = 0.f, al2 = 0.f;
    int win = -1;
    if (live) {
        const int j = p / FS, i = p - j * FS;
        const float px = s0 + (float)i, py = s1 + (float)j;
        const float px1 = px - pw * 0.5f, px2 = px + pw * 0.5f;
        const float py1 = py - ph * 0.5f, py2 = py + ph * 0.5f;

        bool anyhit = false;
        const int nc = s_ncand;
        for (int l = 0; l < nc; l++) {
            const float4 bb = s_cbox[l];
            const float tlx = fmaxf(px1, bb.x);
            const float tly = fmaxf(py1, bb.y);
            const float brx = fminf(px2, bb.z);
            const float bry = fminf(py2, bb.w);
            const float ai = (tlx < brx && tly < bry) ? (brx - tlx) * (bry - tly) : 0.0f;
            anyhit = anyhit || (2.0f * ai > pa + s_carea[l] - ai);
        }
        win = s_win[tid];

        const float obj = (win >= 0) ? 1.0f : (anyhit ? 0.0f : 1.0f);
        if (obj != 0.0f) {
            const float t4 = (win >= 0) ? 1.0f : 0.0f;
            aobj += bcef(s4, t4);
            const float d4 = s4 - t4;
            al2 += d4 * d4;
        }
        if (win >= 0) {
            const float tx = s_tx[win], tw = s_tw[win], th = s_th[win], sv = s_sv[win];
            const float w2 = sv * sv;
            axy += w2 * (bcef(s0, tx) + bcef(s1, tx));
            const float dw = (o2 - tw) * sv, dh = (o3 - th) * sv;
            awh += dw * dw + dh * dh;           // /2 applied at finalize
            const float d0 = s0 - tx, d1 = s1 - tx;
            al2 += d0 * d0 + d1 * d1 + dw * dw + dh * dh;
            const int q = atomicAdd(&s_nw, 1);
            s_wlist[q] = (tid << 16) | win;
        }
    }
    __syncthreads();

    // ---- stage D: cooperative class loss for winner cells (80 lanes gather in parallel) ----
    const int nw = s_nw;
    for (int e = 0; e < nw; e++) {
        const int pk = s_wlist[e];
        const int wtid = pk >> 16, wl = pk & 0xffff;
        if (tid < NCLS) {
            const int cellp = blockIdx.x * BLK + wtid;
            const float sc = sigf(x[((size_t)(b * NA + a) * NCH + 5 + tid) * NCELLP + cellp]);
            const float t = (tid == s_cls[wl]) ? 1.0f : 0.0f;
            acls += bcef(sc, t);
            const float dc = sc - t;
            al2 += dc * dc;
        }
    }

    // ---- deterministic reduction: fp32 wave shuffle -> LDS -> fp64 partial ----
    float v[5] = {axy, awh, aobj, acls, al2};
    #pragma unroll
    for (int k = 0; k < 5; k++) {
        float t = v[k];
        for (int off = 32; off > 0; off >>= 1) t += __shfl_down(t, off, 64);
        v[k] = t;
    }
    const int wave = tid >> 6, lane = tid & 63;
    if (lane == 0) {
        #pragma unroll
        for (int k = 0; k < 5; k++) s_red[wave][k] = v[k];
    }
    __syncthreads();
    if (tid == 0) {
        const int bid = blockIdx.x + GX * (blockIdx.y + NA * blockIdx.z);
        #pragma unroll
        for (int k = 0; k < 5; k++) {
            double s = 0.0;
            for (int w = 0; w < BLK/64; w++) s += (double)s_red[w][k];
            part[(size_t)bid * 5 + k] = s;
        }
    }
}

__global__ __launch_bounds__(256) void k_final(const double* __restrict__ part,
                                               float* __restrict__ out)
{
    __shared__ double s_red[4][5];
    const int tid = threadIdx.x;
    double v[5] = {0, 0, 0, 0, 0};
    for (int r = tid; r < NBLK; r += 256) {
        #pragma unroll
        for (int k = 0; k < 5; k++) v[k] += part[(size_t)r * 5 + k];
    }
    #pragma unroll
    for (int k = 0; k < 5; k++) {
        double t = v[k];
        for (int off = 32; off > 0; off >>= 1) t += __shfl_down(t, off, 64);
        v[k] = t;
    }
    const int wave = tid >> 6, lane = tid & 63;
    if (lane == 0) {
        #pragma unroll
        for (int k = 0; k < 5; k++) s_red[wave][k] = v[k];
    }
    __syncthreads();
    if (tid == 0) {
        double xy = 0, wh = 0, ob = 0, cl = 0, l2 = 0;
        for (int w = 0; w < 4; w++) {
            xy += s_red[w][0]; wh += s_red[w][1]; ob += s_red[w][2];
            cl += s_red[w][3]; l2 += s_red[w][4];
        }
        wh *= 0.5;  // loss_wh = sum/2
        out[0] = (float)(xy + wh + ob + cl);
        out[1] = (float)xy;
        out[2] = (float)wh;
        out[3] = (float)ob;
        out[4] = (float)cl;
        out[5] = (float)l2;
    }
}

extern "C" void kernel_launch(void* const* d_in, const int* in_sizes, int n_in,
                              void* d_out, int out_size, void* d_ws, size_t ws_size,
                              hipStream_t stream) {
    const float* x      = (const float*)d_in[0];
    const float* labels = (const float*)d_in[1];
    double* part = (double*)d_ws;   // NBLK*5 doubles = 44,160 B of scratch

    dim3 grid(GX, NA, NB);
    k_main<<<grid, BLK, 0, stream>>>(x, labels, part);
    k_final<<<1, 256, 0, stream>>>(part, (float*)d_out);
}